// Round 16
// baseline (2173.468 us; speedup 1.0000x reference)
//
#include <hip/hip_runtime.h>

// N=64, T=512, D=H=512.
//   xw = x @ Wx + b   -> d_out (fp32), big MFMA GEMM
//   h_t = tanh(h_{t-1} @ Wh + xw_t) -> overwrites d_out in place
//
// rnn_scan v15 = v13 + column-pair restructure for epilogue/MFMA overlap.
//  r15 lesson: bulk read-lookahead (v14) was null -> stall is the epilogue
//  (~700-1000cy VALU/trans) running AFTER all MFMAs finish (kk-outer order
//  completes all 4 acc columns simultaneously). v15: finish acc{0,1} over all
//  kk first (pair-interleaved, 2-instr dependent spacing), run their fused
//  epilogue while acc{2,3}'s MFMAs still occupy the matrix pipe (separate
//  pipes -> overlap). Per-acc kk order unchanged -> bit-identical output
//  (canary: absmax exactly 0.01843262).
//  Base (r8/r14-verified): 4 blocks x 8 waves (2/SIMD); wave owns 64 cols;
//  bw[12][4]=192 AGPR + kk12-15 in 128KB LDS; h ping-pong 2x16KB swizzled;
//  swapped-operand MFMA; acc init from xw; xw(t+1) prefetch at top;
//  imm-offset LDS bases; ONE raw s_barrier + lgkmcnt(0)/step; NO setprio.
// gemm_xw v2 kept (r13 win).

typedef __attribute__((ext_vector_type(8))) short short8;
typedef __attribute__((ext_vector_type(4))) float f32x4;

#define DIM 512
#define T_S 512

union Frag { uint4 v; short8 s; unsigned short u[8]; };

static __device__ __forceinline__ unsigned short f2bf(float f) {
  union { float f; unsigned u; } v;
  v.f = f;
  unsigned r = v.u + 0x7FFFu + ((v.u >> 16) & 1u);
  return (unsigned short)(r >> 16);
}

static __device__ __forceinline__ unsigned cvt_pk_bf16(float a, float b) {
  unsigned r;
  asm("v_cvt_pk_bf16_f32 %0, %1, %2" : "=v"(r) : "v"(a), "v"(b));
  return r;  // lo16 = bf16(a), hi16 = bf16(b), RNE
}

static __device__ __forceinline__ float fast_tanh(float s) {
  float e = __builtin_amdgcn_exp2f(2.885390082f * s);
  return 1.0f - 2.0f * __builtin_amdgcn_rcpf(e + 1.0f);
}

// ---------------------------------------------------------------------------
// Pack W (512x512 fp32) into bf16 MFMA fragments (A/B-symmetric layout).
// Frag (kk, cc): lane l holds W[k=32kk+8(l>>4)+j][col=16cc+(l&15)], j=0..7,
// at dst[(kk*32+cc)*64 + lane].
// ---------------------------------------------------------------------------
__global__ __launch_bounds__(64) void prepack(const float* __restrict__ Wx,
                                              const float* __restrict__ Wh,
                                              uint4* __restrict__ wxb,
                                              uint4* __restrict__ whb) {
  int bid = blockIdx.x;
  int mat = bid >> 9;
  int idx = bid & 511;
  int kk = idx >> 5, cc = idx & 31;
  int lane = threadIdx.x;
  int lo = lane & 15, hi = lane >> 4;
  const float* src = mat ? Wh : Wx;
  uint4* dst = mat ? whb : wxb;
  int col = cc * 16 + lo;
  int kbase = kk * 32 + hi * 8;
  Frag fr;
#pragma unroll
  for (int j = 0; j < 8; ++j)
    fr.u[j] = f2bf(src[(size_t)(kbase + j) * DIM + col]);
  dst[(kk * 32 + cc) * 64 + lane] = fr.v;
}

// ---------------------------------------------------------------------------
// xw = x @ Wx + b -> out (fp32). M=32768, K=N=512.
// v2: block 256 thr (4 waves), tile 64 rows x 512 cols (x rows read ONCE).
// ---------------------------------------------------------------------------
__global__ __launch_bounds__(256, 2) void gemm_xw(const float* __restrict__ x,
                                                  const uint4* __restrict__ wxb,
                                                  const float* __restrict__ bias,
                                                  float* __restrict__ out) {
  int m = blockIdx.x;
  int wave = threadIdx.x >> 6, lane = threadIdx.x & 63;
  int lo = lane & 15, hi = lane >> 4;
  int rowbase = m * 64;

  f32x4 acc[4][8];
#pragma unroll
  for (int mi = 0; mi < 4; ++mi)
#pragma unroll
    for (int ni = 0; ni < 8; ++ni) acc[mi][ni] = (f32x4){0.f, 0.f, 0.f, 0.f};

  for (int kk = 0; kk < 16; ++kk) {
    short8 afrag[4];
#pragma unroll
    for (int mi = 0; mi < 4; ++mi) {
      const float* ap = x + (size_t)(rowbase + mi * 16 + lo) * DIM + kk * 32 + hi * 8;
      float4 f0 = *(const float4*)ap;
      float4 f1 = *(const float4*)(ap + 4);
      Frag a;
      a.u[0] = f2bf(f0.x); a.u[1] = f2bf(f0.y); a.u[2] = f2bf(f0.z); a.u[3] = f2bf(f0.w);
      a.u[4] = f2bf(f1.x); a.u[5] = f2bf(f1.y); a.u[6] = f2bf(f1.z); a.u[7] = f2bf(f1.w);
      afrag[mi] = a.s;
    }
#pragma unroll
    for (int ni = 0; ni < 8; ++ni) {
      int cc = wave * 8 + ni;
      Frag b;
      b.v = wxb[(kk * 32 + cc) * 64 + lane];
#pragma unroll
      for (int mi = 0; mi < 4; ++mi)
        acc[mi][ni] = __builtin_amdgcn_mfma_f32_16x16x32_bf16(afrag[mi], b.s, acc[mi][ni], 0, 0, 0);
    }
  }
#pragma unroll
  for (int ni = 0; ni < 8; ++ni) {
    int col = wave * 128 + ni * 16 + lo;
    float bv = bias[col];
#pragma unroll
    for (int mi = 0; mi < 4; ++mi)
#pragma unroll
      for (int r = 0; r < 4; ++r) {
        int row = rowbase + mi * 16 + hi * 4 + r;
        out[(size_t)row * DIM + col] = acc[mi][ni][r] + bv;
      }
  }
}

// ---------------------------------------------------------------------------
// Recurrent scan v15. grid = 4 blocks x 512 thr (8 waves, 2/SIMD).
// Block g: batch rows [16g,16g+16), all 512 cols. Wave w: cols [64w,64w+64).
// h in LDS as [buf][n][k] bf16, XOR-swizzled: byte = n*1024 + ((k*2)^((n&7)<<4)).
// ---------------------------------------------------------------------------
__shared__ uint4 wlds[4][32][64];             // 128 KB: Wh kk=12..15
__shared__ unsigned short hbuf2[2][16 * 512]; // 32 KB ping/pong

template <int BUF>
static __device__ __forceinline__ void step_body(
    int t, int w, int lane, const uint4 (&bw)[12][4],
    const uint4* const (&rdp)[8], uint2* const (&wrp)[4],
    float (&xwv)[16], float*& gp) {
  // acc starts at xw (lane: n=lo, cols 64w + 16i + 4hi + r)
  f32x4 acc[4];
#pragma unroll
  for (int i = 0; i < 4; ++i)
    acc[i] = (f32x4){xwv[i * 4 + 0], xwv[i * 4 + 1], xwv[i * 4 + 2], xwv[i * 4 + 3]};

  // prefetch xw(t+1): 4x dwordx4
  const float* lp = gp + ((t < T_S - 1) ? DIM : 0);
#pragma unroll
  for (int i = 0; i < 4; ++i) {
    float4 f = *(const float4*)(lp + i * 16);
    xwv[i * 4 + 0] = f.x; xwv[i * 4 + 1] = f.y;
    xwv[i * 4 + 2] = f.z; xwv[i * 4 + 3] = f.w;
  }

  // all 16 h-frag reads up front (required: frags feed both column pairs)
  Frag hfr[16];
#pragma unroll
  for (int kk = 0; kk < 16; ++kk)
    hfr[kk].v = rdp[kk & 7][((kk & 8) ? 32 : 0) + BUF * 1024];

  // ---- pair 0: acc[0], acc[1] over all kk, then their fused epilogue ----
  // (dependent-MFMA spacing = 2 instr; per-acc kk order 0..15 unchanged)
#pragma unroll
  for (int kk = 0; kk < 12; ++kk) {
    Frag a0; a0.v = bw[kk][0];
    Frag a1; a1.v = bw[kk][1];
    acc[0] = __builtin_amdgcn_mfma_f32_16x16x32_bf16(a0.s, hfr[kk].s, acc[0], 0, 0, 0);
    acc[1] = __builtin_amdgcn_mfma_f32_16x16x32_bf16(a1.s, hfr[kk].s, acc[1], 0, 0, 0);
  }
#pragma unroll
  for (int kk = 12; kk < 16; ++kk) {
    Frag a0; a0.v = wlds[kk - 12][w * 4 + 0][lane];
    Frag a1; a1.v = wlds[kk - 12][w * 4 + 1][lane];
    acc[0] = __builtin_amdgcn_mfma_f32_16x16x32_bf16(a0.s, hfr[kk].s, acc[0], 0, 0, 0);
    acc[1] = __builtin_amdgcn_mfma_f32_16x16x32_bf16(a1.s, hfr[kk].s, acc[1], 0, 0, 0);
  }
  // epilogue pair 0 (overlaps pair-1 MFMAs below on the VALU/trans pipes)
#pragma unroll
  for (int i = 0; i < 2; ++i) {
    float h0 = fast_tanh(acc[i][0]);
    float h1 = fast_tanh(acc[i][1]);
    float h2 = fast_tanh(acc[i][2]);
    float h3 = fast_tanh(acc[i][3]);
    *(float4*)(gp + i * 16) = (float4){h0, h1, h2, h3};
    uint2 u;
    u.x = cvt_pk_bf16(h0, h1);
    u.y = cvt_pk_bf16(h2, h3);
    wrp[i][(BUF ^ 1) * 2048] = u;
  }

  // ---- pair 1: acc[2], acc[3] ----
#pragma unroll
  for (int kk = 0; kk < 12; ++kk) {
    Frag a2; a2.v = bw[kk][2];
    Frag a3; a3.v = bw[kk][3];
    acc[2] = __builtin_amdgcn_mfma_f32_16x16x32_bf16(a2.s, hfr[kk].s, acc[2], 0, 0, 0);
    acc[3] = __builtin_amdgcn_mfma_f32_16x16x32_bf16(a3.s, hfr[kk].s, acc[3], 0, 0, 0);
  }
#pragma unroll
  for (int kk = 12; kk < 16; ++kk) {
    Frag a2; a2.v = wlds[kk - 12][w * 4 + 2][lane];
    Frag a3; a3.v = wlds[kk - 12][w * 4 + 3][lane];
    acc[2] = __builtin_amdgcn_mfma_f32_16x16x32_bf16(a2.s, hfr[kk].s, acc[2], 0, 0, 0);
    acc[3] = __builtin_amdgcn_mfma_f32_16x16x32_bf16(a3.s, hfr[kk].s, acc[3], 0, 0, 0);
  }
  // epilogue pair 1
#pragma unroll
  for (int i = 2; i < 4; ++i) {
    float h0 = fast_tanh(acc[i][0]);
    float h1 = fast_tanh(acc[i][1]);
    float h2 = fast_tanh(acc[i][2]);
    float h3 = fast_tanh(acc[i][3]);
    *(float4*)(gp + i * 16) = (float4){h0, h1, h2, h3};
    uint2 u;
    u.x = cvt_pk_bf16(h0, h1);
    u.y = cvt_pk_bf16(h2, h3);
    wrp[i][(BUF ^ 1) * 2048] = u;
  }
  gp += DIM;

  // one barrier per step: LDS h-writes visible; no vmem drain
  asm volatile("s_waitcnt lgkmcnt(0)" ::: "memory");
  __builtin_amdgcn_sched_barrier(0);
  __builtin_amdgcn_s_barrier();
  __builtin_amdgcn_sched_barrier(0);
}

__global__ __launch_bounds__(512, 2) void rnn_scan(const float* __restrict__ h0,
                                                   const uint4* __restrict__ whb,
                                                   float* __restrict__ out) {
  int g = blockIdx.x;
  int w = threadIdx.x >> 6, lane = threadIdx.x & 63;
  int lo = lane & 15, hi = lane >> 4;
  int msk = (lo & 7) << 4;

  // AGPR-resident Wh: kk 0..11 x this wave's 4 col-tiles = 192 regs
  uint4 bw[12][4];
#pragma unroll
  for (int kk = 0; kk < 12; ++kk)
#pragma unroll
    for (int i = 0; i < 4; ++i)
      bw[kk][i] = whb[(kk * 32 + (w * 4 + i)) * 64 + lane];

  // LDS-resident Wh: kk 12..15, all 32 cc (coalesced cooperative stage)
#pragma unroll
  for (int e = 0; e < 16; ++e) {
    int idx = e * 512 + threadIdx.x;
    int s = idx >> 11, rem = idx & 2047;
    wlds[s][rem >> 6][rem & 63] = whb[((12 + s) * 32 + (rem >> 6)) * 64 + (rem & 63)];
  }

  // loop-invariant LDS addresses (buffer 0 bases; +16384B via imm for buffer 1)
  const uint4* rdp[8];
#pragma unroll
  for (int kk = 0; kk < 8; ++kk)
    rdp[kk] = (const uint4*)((const char*)hbuf2 + lo * 1024 + ((kk * 64 + hi * 16) ^ msk));
  uint2* wrp[4];
#pragma unroll
  for (int i = 0; i < 4; ++i)
    wrp[i] = (uint2*)((char*)hbuf2 + lo * 1024 + ((128 * w + 32 * i + 8 * hi) ^ msk));

  // h_0 into buffer 0
#pragma unroll
  for (int i = 0; i < 4; ++i) {
    const float* hp = h0 + (size_t)(g * 16 + lo) * DIM + w * 64 + i * 16 + hi * 4;
    float4 f = *(const float4*)hp;
    uint2 u;
    u.x = (unsigned)f2bf(f.x) | ((unsigned)f2bf(f.y) << 16);
    u.y = (unsigned)f2bf(f.z) | ((unsigned)f2bf(f.w) << 16);
    wrp[i][0] = u;
  }

  // running global pointer: lane -> out[n=16g+lo][t=0][64w + 4hi]
  float* gp = out + ((size_t)(g * 16 + lo) * T_S) * DIM + w * 64 + hi * 4;

  // prime xw for t=0
  float xwv[16];
#pragma unroll
  for (int i = 0; i < 4; ++i) {
    float4 f = *(const float4*)(gp + i * 16);
    xwv[i * 4 + 0] = f.x; xwv[i * 4 + 1] = f.y;
    xwv[i * 4 + 2] = f.z; xwv[i * 4 + 3] = f.w;
  }

  __syncthreads();  // heavy barrier once before the loop

#pragma unroll 1
  for (int t = 0; t < T_S; t += 2) {
    step_body<0>(t,     w, lane, bw, rdp, wrp, xwv, gp);
    step_body<1>(t + 1, w, lane, bw, rdp, wrp, xwv, gp);
  }
}

// ---------------------------------------------------------------------------
extern "C" void kernel_launch(void* const* d_in, const int* in_sizes, int n_in,
                              void* d_out, int out_size, void* d_ws, size_t ws_size,
                              hipStream_t stream) {
  const float* x  = (const float*)d_in[0];
  const float* h0 = (const float*)d_in[1];
  const float* Wx = (const float*)d_in[2];
  const float* Wh = (const float*)d_in[3];
  const float* b  = (const float*)d_in[4];
  float* out = (float*)d_out;

  char* ws = (char*)d_ws;
  uint4* whb = (uint4*)ws;                  // 512 KB
  uint4* wxb = (uint4*)(ws + 524288);       // 512 KB

  prepack<<<1024, 64, 0, stream>>>(Wx, Wh, wxb, whb);
  gemm_xw<<<512, 256, 0, stream>>>(x, wxb, b, out);
  rnn_scan<<<4, 512, 0, stream>>>(h0, whb, out);
}

// Round 17
// 1126.071 us; speedup vs baseline: 1.9301x; 1.9301x over previous
//
#include <hip/hip_runtime.h>

// N=64, T=512, D=H=512.
//   xw = x @ Wx + b   -> d_out (fp32), big MFMA GEMM
//   h_t = tanh(h_{t-1} @ Wh + xw_t) -> overwrites d_out in place
//
// FINAL STRUCTURE (round-17 revert to round-14 best: 1125us total).
// rnn_scan = v7/v13: the measured optimum after 7 scheduling experiments on
// this structure (setprio, bulk prefetch, pair-split, L2 streaming, 224/256
// AGPR residency, cross-block exchange) ALL regressed or were null.
//  - 4 blocks x 8 waves (2 waves/SIMD); block g owns batch rows [16g,16g+16),
//    wave w owns cols [64w,64w+64).
//  - Wh: bw[12][4] = 192 frags in AGPR + kk12-15 in 128 KB LDS (the 12/4
//    split is the optimum of the residency axis, r9-r12).
//  - h ping-pong 2x16 KB LDS, XOR-swizzled (byte = n*1024 + ((k*2)^((n&7)<<4))).
//  - swapped-operand MFMA: D = mfma(A=Wh_frag, B=h_frag) -> lane owns batch
//    row n=lo and 4 consecutive cols per acc group -> vector epilogue
//    (cvt_pk_bf16 + ds_write_b64 + float4 global store).
//  - acc init from xw; xw(t+1) prefetched at step top (4x dwordx4).
//  - ONE raw s_barrier + lgkmcnt(0) per step (global traffic in flight).
// gemm_xw v2: 64x512 block tile (x rows read once) - r13 win.
// Scan is latency-bound on 4/256 CUs (serial recurrence, cross-CU exchange
// costs 2.4-8x - measured r2/r9); chip-wide counters read ~1% by design.

typedef __attribute__((ext_vector_type(8))) short short8;
typedef __attribute__((ext_vector_type(4))) float f32x4;

#define DIM 512
#define T_S 512

union Frag { uint4 v; short8 s; unsigned short u[8]; };

static __device__ __forceinline__ unsigned short f2bf(float f) {
  union { float f; unsigned u; } v;
  v.f = f;
  unsigned r = v.u + 0x7FFFu + ((v.u >> 16) & 1u);
  return (unsigned short)(r >> 16);
}

static __device__ __forceinline__ unsigned cvt_pk_bf16(float a, float b) {
  unsigned r;
  asm("v_cvt_pk_bf16_f32 %0, %1, %2" : "=v"(r) : "v"(a), "v"(b));
  return r;  // lo16 = bf16(a), hi16 = bf16(b), RNE
}

static __device__ __forceinline__ float fast_tanh(float s) {
  float e = __builtin_amdgcn_exp2f(2.885390082f * s);
  return 1.0f - 2.0f * __builtin_amdgcn_rcpf(e + 1.0f);
}

// ---------------------------------------------------------------------------
// Pack W (512x512 fp32) into bf16 MFMA fragments (A/B-symmetric layout).
// Frag (kk, cc): lane l holds W[k=32kk+8(l>>4)+j][col=16cc+(l&15)], j=0..7,
// at dst[(kk*32+cc)*64 + lane].
// ---------------------------------------------------------------------------
__global__ __launch_bounds__(64) void prepack(const float* __restrict__ Wx,
                                              const float* __restrict__ Wh,
                                              uint4* __restrict__ wxb,
                                              uint4* __restrict__ whb) {
  int bid = blockIdx.x;
  int mat = bid >> 9;
  int idx = bid & 511;
  int kk = idx >> 5, cc = idx & 31;
  int lane = threadIdx.x;
  int lo = lane & 15, hi = lane >> 4;
  const float* src = mat ? Wh : Wx;
  uint4* dst = mat ? whb : wxb;
  int col = cc * 16 + lo;
  int kbase = kk * 32 + hi * 8;
  Frag fr;
#pragma unroll
  for (int j = 0; j < 8; ++j)
    fr.u[j] = f2bf(src[(size_t)(kbase + j) * DIM + col]);
  dst[(kk * 32 + cc) * 64 + lane] = fr.v;
}

// ---------------------------------------------------------------------------
// xw = x @ Wx + b -> out (fp32). M=32768, K=N=512.
// v2: block 256 thr (4 waves), tile 64 rows x 512 cols (x rows read ONCE).
// Wave w: cc 8w..8w+7. grid = 512.
// ---------------------------------------------------------------------------
__global__ __launch_bounds__(256, 2) void gemm_xw(const float* __restrict__ x,
                                                  const uint4* __restrict__ wxb,
                                                  const float* __restrict__ bias,
                                                  float* __restrict__ out) {
  int m = blockIdx.x;
  int wave = threadIdx.x >> 6, lane = threadIdx.x & 63;
  int lo = lane & 15, hi = lane >> 4;
  int rowbase = m * 64;

  f32x4 acc[4][8];
#pragma unroll
  for (int mi = 0; mi < 4; ++mi)
#pragma unroll
    for (int ni = 0; ni < 8; ++ni) acc[mi][ni] = (f32x4){0.f, 0.f, 0.f, 0.f};

  for (int kk = 0; kk < 16; ++kk) {
    short8 afrag[4];
#pragma unroll
    for (int mi = 0; mi < 4; ++mi) {
      const float* ap = x + (size_t)(rowbase + mi * 16 + lo) * DIM + kk * 32 + hi * 8;
      float4 f0 = *(const float4*)ap;
      float4 f1 = *(const float4*)(ap + 4);
      Frag a;
      a.u[0] = f2bf(f0.x); a.u[1] = f2bf(f0.y); a.u[2] = f2bf(f0.z); a.u[3] = f2bf(f0.w);
      a.u[4] = f2bf(f1.x); a.u[5] = f2bf(f1.y); a.u[6] = f2bf(f1.z); a.u[7] = f2bf(f1.w);
      afrag[mi] = a.s;
    }
#pragma unroll
    for (int ni = 0; ni < 8; ++ni) {
      int cc = wave * 8 + ni;
      Frag b;
      b.v = wxb[(kk * 32 + cc) * 64 + lane];
#pragma unroll
      for (int mi = 0; mi < 4; ++mi)
        acc[mi][ni] = __builtin_amdgcn_mfma_f32_16x16x32_bf16(afrag[mi], b.s, acc[mi][ni], 0, 0, 0);
    }
  }
#pragma unroll
  for (int ni = 0; ni < 8; ++ni) {
    int col = wave * 128 + ni * 16 + lo;
    float bv = bias[col];
#pragma unroll
    for (int mi = 0; mi < 4; ++mi)
#pragma unroll
      for (int r = 0; r < 4; ++r) {
        int row = rowbase + mi * 16 + hi * 4 + r;
        out[(size_t)row * DIM + col] = acc[mi][ni][r] + bv;
      }
  }
}

// ---------------------------------------------------------------------------
// Recurrent scan (v7/v13 verbatim). grid = 4 blocks x 512 thr (8 waves, 2/SIMD).
// ---------------------------------------------------------------------------
__shared__ uint4 wlds[4][32][64];             // 128 KB: Wh kk=12..15
__shared__ unsigned short hbuf2[2][16 * 512]; // 32 KB ping/pong

template <int BUF>
static __device__ __forceinline__ void step_body(
    int t, int w, int lane, const uint4 (&bw)[12][4],
    const uint4* const (&rdp)[8], uint2* const (&wrp)[4],
    float (&xwv)[16], float*& gp) {
  // acc starts at xw (lane: n=lo, cols 64w + 16i + 4hi + r)
  f32x4 acc[4];
#pragma unroll
  for (int i = 0; i < 4; ++i)
    acc[i] = (f32x4){xwv[i * 4 + 0], xwv[i * 4 + 1], xwv[i * 4 + 2], xwv[i * 4 + 3]};

  // prefetch xw(t+1): 4x dwordx4, issued before MFMA phase
  const float* lp = gp + ((t < T_S - 1) ? DIM : 0);
#pragma unroll
  for (int i = 0; i < 4; ++i) {
    float4 f = *(const float4*)(lp + i * 16);
    xwv[i * 4 + 0] = f.x; xwv[i * 4 + 1] = f.y;
    xwv[i * 4 + 2] = f.z; xwv[i * 4 + 3] = f.w;
  }

  // kk 0..11: AGPR-resident weights as A; h frag as B (imm-offset reads)
#pragma unroll
  for (int kk = 0; kk < 12; ++kk) {
    Frag hf; hf.v = rdp[kk & 7][((kk & 8) ? 32 : 0) + BUF * 1024];
#pragma unroll
    for (int i = 0; i < 4; ++i) {
      Frag a; a.v = bw[kk][i];
      acc[i] = __builtin_amdgcn_mfma_f32_16x16x32_bf16(a.s, hf.s, acc[i], 0, 0, 0);
    }
  }
  // kk 12..15: LDS-resident weights (lane-contiguous uint4, conflict-free)
#pragma unroll
  for (int kk = 12; kk < 16; ++kk) {
    Frag hf; hf.v = rdp[kk & 7][32 + BUF * 1024];
#pragma unroll
    for (int i = 0; i < 4; ++i) {
      Frag a; a.v = wlds[kk - 12][w * 4 + i][lane];
      acc[i] = __builtin_amdgcn_mfma_f32_16x16x32_bf16(a.s, hf.s, acc[i], 0, 0, 0);
    }
  }

  // epilogue: lane owns n=lo, 4 consecutive cols per acc group
#pragma unroll
  for (int i = 0; i < 4; ++i) {
    float h0 = fast_tanh(acc[i][0]);
    float h1 = fast_tanh(acc[i][1]);
    float h2 = fast_tanh(acc[i][2]);
    float h3 = fast_tanh(acc[i][3]);
    *(float4*)(gp + i * 16) = (float4){h0, h1, h2, h3};   // out row n, 16B
    uint2 u;
    u.x = cvt_pk_bf16(h0, h1);
    u.y = cvt_pk_bf16(h2, h3);
    wrp[i][(BUF ^ 1) * 2048] = u;                          // ds_write_b64
  }
  gp += DIM;

  // one barrier per step: LDS h-writes visible; no vmem drain
  asm volatile("s_waitcnt lgkmcnt(0)" ::: "memory");
  __builtin_amdgcn_sched_barrier(0);
  __builtin_amdgcn_s_barrier();
  __builtin_amdgcn_sched_barrier(0);
}

__global__ __launch_bounds__(512, 2) void rnn_scan(const float* __restrict__ h0,
                                                   const uint4* __restrict__ whb,
                                                   float* __restrict__ out) {
  int g = blockIdx.x;
  int w = threadIdx.x >> 6, lane = threadIdx.x & 63;
  int lo = lane & 15, hi = lane >> 4;
  int msk = (lo & 7) << 4;

  // AGPR-resident Wh: kk 0..11 x this wave's 4 col-tiles = 192 regs
  uint4 bw[12][4];
#pragma unroll
  for (int kk = 0; kk < 12; ++kk)
#pragma unroll
    for (int i = 0; i < 4; ++i)
      bw[kk][i] = whb[(kk * 32 + (w * 4 + i)) * 64 + lane];

  // LDS-resident Wh: kk 12..15, all 32 cc (coalesced cooperative stage)
#pragma unroll
  for (int e = 0; e < 16; ++e) {
    int idx = e * 512 + threadIdx.x;
    int s = idx >> 11, rem = idx & 2047;
    wlds[s][rem >> 6][rem & 63] = whb[((12 + s) * 32 + (rem >> 6)) * 64 + (rem & 63)];
  }

  // loop-invariant LDS addresses (buffer 0 bases; +16384B via imm for buffer 1)
  // read (B=h frag): byte = lo*1024 + ((kk*64 + hi*16) ^ msk), kk=0..7
  const uint4* rdp[8];
#pragma unroll
  for (int kk = 0; kk < 8; ++kk)
    rdp[kk] = (const uint4*)((const char*)hbuf2 + lo * 1024 + ((kk * 64 + hi * 16) ^ msk));
  // write: byte = lo*1024 + (((64w + 16i + 4hi)*2) ^ msk), i=0..3 bases
  uint2* wrp[4];
#pragma unroll
  for (int i = 0; i < 4; ++i)
    wrp[i] = (uint2*)((char*)hbuf2 + lo * 1024 + ((128 * w + 32 * i + 8 * hi) ^ msk));

  // h_0 into buffer 0: lane loads h0[n=lo][c..c+3], packs, b64-writes
#pragma unroll
  for (int i = 0; i < 4; ++i) {
    const float* hp = h0 + (size_t)(g * 16 + lo) * DIM + w * 64 + i * 16 + hi * 4;
    float4 f = *(const float4*)hp;
    uint2 u;
    u.x = (unsigned)f2bf(f.x) | ((unsigned)f2bf(f.y) << 16);
    u.y = (unsigned)f2bf(f.z) | ((unsigned)f2bf(f.w) << 16);
    wrp[i][0] = u;
  }

  // running global pointer: lane -> out[n=16g+lo][t=0][64w + 4hi]
  float* gp = out + ((size_t)(g * 16 + lo) * T_S) * DIM + w * 64 + hi * 4;

  // prime xw for t=0
  float xwv[16];
#pragma unroll
  for (int i = 0; i < 4; ++i) {
    float4 f = *(const float4*)(gp + i * 16);
    xwv[i * 4 + 0] = f.x; xwv[i * 4 + 1] = f.y;
    xwv[i * 4 + 2] = f.z; xwv[i * 4 + 3] = f.w;
  }

  __syncthreads();  // heavy barrier once before the loop

#pragma unroll 1
  for (int t = 0; t < T_S; t += 2) {
    step_body<0>(t,     w, lane, bw, rdp, wrp, xwv, gp);
    step_body<1>(t + 1, w, lane, bw, rdp, wrp, xwv, gp);
  }
}

// ---------------------------------------------------------------------------
extern "C" void kernel_launch(void* const* d_in, const int* in_sizes, int n_in,
                              void* d_out, int out_size, void* d_ws, size_t ws_size,
                              hipStream_t stream) {
  const float* x  = (const float*)d_in[0];
  const float* h0 = (const float*)d_in[1];
  const float* Wx = (const float*)d_in[2];
  const float* Wh = (const float*)d_in[3];
  const float* b  = (const float*)d_in[4];
  float* out = (float*)d_out;

  char* ws = (char*)d_ws;
  uint4* whb = (uint4*)ws;                  // 512 KB
  uint4* wxb = (uint4*)(ws + 524288);       // 512 KB

  prepack<<<1024, 64, 0, stream>>>(Wx, Wh, wxb, whb);
  gemm_xw<<<512, 256, 0, stream>>>(x, wxb, b, out);
  rnn_scan<<<4, 512, 0, stream>>>(h0, whb, out);
}